// Round 14
// baseline (205.260 us; speedup 1.0000x reference)
//
#include <hip/hip_runtime.h>
#include <math.h>

#define NTOK 16384
#define DIM  4096
#define NE   64
#define TOPK 8
#define NSL  (DIM / 32)          // 128 k32-slices
#define ROUTE_SCALE 2.5f

typedef __attribute__((ext_vector_type(8))) short short8v;
typedef __attribute__((ext_vector_type(4))) float f32x4;

// exact 3-term bf16 truncation split of 8 f32, packed as 3x short8 (bf16) frags
__device__ __forceinline__ void split3_pack(const float* v, uint4& b0, uint4& b1, uint4& b2)
{
    uint p0[8], p1[8], p2[8];
#pragma unroll
    for (int j = 0; j < 8; ++j) {
        const float xv = v[j];
        const uint  u0 = __float_as_uint(xv) & 0xffff0000u;
        const float f0 = __uint_as_float(u0);
        const float r  = xv - f0;                       // exact
        const uint  u1 = __float_as_uint(r) & 0xffff0000u;
        const float f1 = __uint_as_float(u1);
        const float r2 = r - f1;                        // exact, fits bf16
        const uint  u2 = __float_as_uint(r2) & 0xffff0000u;
        p0[j] = u0; p1[j] = u1; p2[j] = u2;
    }
    b0 = make_uint4(p0[1] | (p0[0] >> 16), p0[3] | (p0[2] >> 16),
                    p0[5] | (p0[4] >> 16), p0[7] | (p0[6] >> 16));
    b1 = make_uint4(p1[1] | (p1[0] >> 16), p1[3] | (p1[2] >> 16),
                    p1[5] | (p1[4] >> 16), p1[7] | (p1[6] >> 16));
    b2 = make_uint4(p2[1] | (p2[0] >> 16), p2[3] | (p2[2] >> 16),
                    p2[5] | (p2[4] >> 16), p2[7] | (p2[6] >> 16));
}

// ---- prep: w -> frag-ready bf16 splits (UNCHANGED, proven r4-r13) ----
__global__ __launch_bounds__(256)
void prep_w(const float* __restrict__ gw, uint4* __restrict__ wS)
{
    const int tid  = blockIdx.x * 256 + threadIdx.x;   // 32768 total
    const int lane = tid & 63;
    const int nt   = (tid >> 6) & 3;
    const int ks   = tid >> 8;                         // 0..127
    const int e    = nt * 16 + (lane & 15);
    const int kb   = ks * 32 + (lane >> 4) * 8;
    float v[8];
    *(float4*)&v[0] = *(const float4*)&gw[(size_t)e * DIM + kb];
    *(float4*)&v[4] = *(const float4*)&gw[(size_t)e * DIM + kb + 4];
    uint4 b0, b1, b2;
    split3_pack(v, b0, b1, b2);
    const size_t base = (size_t)(ks * 4 + nt) * 3 * 64 + lane;
    wS[base] = b0; wS[base + 64] = b1; wS[base + 128] = b2;
}

#define MFMA6(A0, A1, A2, B0, B1, B2, ACC) do {                              \
    ACC = __builtin_amdgcn_mfma_f32_16x16x32_bf16(A2, B0, ACC, 0, 0, 0);     \
    ACC = __builtin_amdgcn_mfma_f32_16x16x32_bf16(A1, B1, ACC, 0, 0, 0);     \
    ACC = __builtin_amdgcn_mfma_f32_16x16x32_bf16(A0, B2, ACC, 0, 0, 0);     \
    ACC = __builtin_amdgcn_mfma_f32_16x16x32_bf16(A1, B0, ACC, 0, 0, 0);     \
    ACC = __builtin_amdgcn_mfma_f32_16x16x32_bf16(A0, B1, ACC, 0, 0, 0);     \
    ACC = __builtin_amdgcn_mfma_f32_16x16x32_bf16(A0, B0, ACC, 0, 0, 0);     \
} while (0)

// ---- fused: 4 lightweight waves (16 tok x 16 exp x full K), no LDS/barriers
// in hot loop; x 4-slice-deep, B 4-slot (3-slice lead); 4 waves/SIMD target.
__global__ __launch_bounds__(256, 4)
void router_fused(const float* __restrict__ x, const uint4* __restrict__ wS,
                  const float* __restrict__ bias, float* __restrict__ out)
{
    __shared__ float sc[16][NE + 1];   // 4.2 KB
    __shared__ int   hist[NE];

    const int t    = threadIdx.x;
    const int lane = t & 63;
    const int wv   = __builtin_amdgcn_readfirstlane(t >> 6);   // 0..3 expert quarter
    const int r15  = lane & 15;
    const int g    = lane >> 4;
    const int tok0 = blockIdx.x * 16;

    if (t < NE) hist[t] = 0;

    // A-frag source: lane (r15,g) = row r15, k-elems [g*8, g*8+8) of each slice.
    // Per slice each row consumes exactly one 128B line; 4 waves share lines via L1.
    const float* xlane = x + (size_t)(tok0 + r15) * DIM + g * 8;
    const uint4* wq    = wS + wv * 192 + lane;   // slice stride 768 uint4

    f32x4 acc = {0.f, 0.f, 0.f, 0.f};

    float xb0[8], xb1[8], xb2[8], xb3[8];   // 4-slice x prefetch ring (static slots)
    uint4 Ba[3], Bb[3], Bc[3], Bd[3];       // 4-slot B ring (3-slice lead)

#define XL(X, s) do {                                                        \
        *(float4*)&X[0] = *(const float4*)(xlane + (size_t)(s) * 32);        \
        *(float4*)&X[4] = *(const float4*)(xlane + (size_t)(s) * 32 + 4);    \
    } while (0)
#define BL(B, s) do {                                                        \
        B[0] = wq[(size_t)(s) * 768];                                        \
        B[1] = wq[(size_t)(s) * 768 + 64];                                   \
        B[2] = wq[(size_t)(s) * 768 + 128];                                  \
    } while (0)
#define CS(X, B) do {                                                        \
        uint4 a0u, a1u, a2u;                                                 \
        split3_pack(X, a0u, a1u, a2u);                                       \
        MFMA6(*(short8v*)&a0u, *(short8v*)&a1u, *(short8v*)&a2u,             \
              *(const short8v*)&B[0], *(const short8v*)&B[1],                \
              *(const short8v*)&B[2], acc);                                  \
    } while (0)

    // prologue: 4 slices of x, 4 slices of B in flight
    XL(xb0, 0); XL(xb1, 1); XL(xb2, 2); XL(xb3, 3);
    BL(Ba, 0);  BL(Bb, 1);  BL(Bc, 2);  BL(Bd, 3);

    // main: compute s..s+3, refill slots with s+4..s+7 (last iter s=120 -> 124..127)
#pragma unroll 1
    for (int s = 0; s < NSL - 4; s += 4) {
        CS(xb0, Ba); XL(xb0, s + 4); BL(Ba, s + 4);
        CS(xb1, Bb); XL(xb1, s + 5); BL(Bb, s + 5);
        CS(xb2, Bc); XL(xb2, s + 6); BL(Bc, s + 6);
        CS(xb3, Bd); XL(xb3, s + 7); BL(Bd, s + 7);
    }
    // tail: slices 124..127, nothing left to issue
    CS(xb0, Ba); CS(xb1, Bb); CS(xb2, Bc); CS(xb3, Bd);

#undef XL
#undef BL
#undef CS

    // ---- scores (C/D layout proven r4-r13: token = g*4+q, expert = wv*16+r15) ----
#pragma unroll
    for (int q = 0; q < 4; ++q)
        sc[g * 4 + q][wv * 16 + r15] = 1.f / (1.f + expf(-acc[q]));
    __syncthreads();

    // ---- top-8: wave wv handles tokens wv*4..wv*4+3; lane == expert (proven) ----
    const float bias_l = bias[lane];
#pragma unroll 1
    for (int i = 0; i < 4; ++i) {
        const int tok = wv * 4 + i;
        const float s = sc[tok][lane];
        float myv  = s + bias_l;
        float outv = 0.f;
        int   outi = 0;
        float sum  = 0.f;
#pragma unroll
        for (int k = 0; k < TOPK; ++k) {
            float cv = myv;
            int   ci = lane;
#pragma unroll
            for (int off = 32; off; off >>= 1) {
                float ov = __shfl_xor(cv, off, 64);
                int   oi = __shfl_xor(ci, off, 64);
                if (ov > cv || (ov == cv && oi < ci)) { cv = ov; ci = oi; }
            }
            float ts = __shfl(s, ci, 64);      // unbiased score of winner
            sum += ts;
            if (lane == k)  { outv = ts; outi = ci; }
            if (lane == ci) { myv = -1e30f; }
        }
        const float denom = sum + 1e-20f;
        const size_t gt = (size_t)tok0 + tok;
        if (lane < TOPK) {
            out[gt * TOPK + lane] = (outv / denom) * ROUTE_SCALE;
            out[(size_t)NTOK * TOPK + gt * TOPK + lane] = (float)outi;
            atomicAdd(&hist[outi], 1);
        }
    }

    __syncthreads();
    if (t < NE) {
        int cgt = hist[t];
        if (cgt) atomicAdd(&out[(size_t)NTOK * TOPK * 2 + t], (float)cgt);
    }
}

extern "C" void kernel_launch(void* const* d_in, const int* in_sizes, int n_in,
                              void* d_out, int out_size, void* d_ws, size_t ws_size,
                              hipStream_t stream)
{
    const float* x    = (const float*)d_in[0];
    const float* gw   = (const float*)d_in[1];
    const float* bias = (const float*)d_in[2];
    float* out = (float*)d_out;
    uint4* wS  = (uint4*)d_ws;   // 1.5 MB

    // histogram region must start at zero every call
    hipMemsetAsync(out + (size_t)NTOK * TOPK * 2, 0, NE * sizeof(float), stream);

    prep_w<<<128, 256, 0, stream>>>(gw, wS);
    router_fused<<<NTOK / 16, 256, 0, stream>>>(x, wS, bias, out);
}

// Round 16
// 99.814 us; speedup vs baseline: 2.0564x; 2.0564x over previous
//
#include <hip/hip_runtime.h>
#include <math.h>

#define NTOK 16384
#define DIM  4096
#define NE   64
#define TOPK 8
#define SPLITK 8
#define NSPW (DIM / 32 / SPLITK)   // 16 k32-slices per wave
#define ROUTE_SCALE 2.5f

typedef __attribute__((ext_vector_type(8))) short short8v;
typedef __attribute__((ext_vector_type(4))) float f32x4;

// exact 3-term bf16 truncation split of 8 f32, packed as 3x short8 (bf16) frags
__device__ __forceinline__ void split3_pack(const float* v, uint4& b0, uint4& b1, uint4& b2)
{
    uint p0[8], p1[8], p2[8];
#pragma unroll
    for (int j = 0; j < 8; ++j) {
        const float xv = v[j];
        const uint  u0 = __float_as_uint(xv) & 0xffff0000u;
        const float f0 = __uint_as_float(u0);
        const float r  = xv - f0;                       // exact
        const uint  u1 = __float_as_uint(r) & 0xffff0000u;
        const float f1 = __uint_as_float(u1);
        const float r2 = r - f1;                        // exact, fits bf16
        const uint  u2 = __float_as_uint(r2) & 0xffff0000u;
        p0[j] = u0; p1[j] = u1; p2[j] = u2;
    }
    b0 = make_uint4(p0[1] | (p0[0] >> 16), p0[3] | (p0[2] >> 16),
                    p0[5] | (p0[4] >> 16), p0[7] | (p0[6] >> 16));
    b1 = make_uint4(p1[1] | (p1[0] >> 16), p1[3] | (p1[2] >> 16),
                    p1[5] | (p1[4] >> 16), p1[7] | (p1[6] >> 16));
    b2 = make_uint4(p2[1] | (p2[0] >> 16), p2[3] | (p2[2] >> 16),
                    p2[5] | (p2[4] >> 16), p2[7] | (p2[6] >> 16));
}

// ---- prep: w -> frag-ready bf16 splits (UNCHANGED, proven r4-r14) ----
__global__ __launch_bounds__(256)
void prep_w(const float* __restrict__ gw, uint4* __restrict__ wS)
{
    const int tid  = blockIdx.x * 256 + threadIdx.x;   // 32768 total
    const int lane = tid & 63;
    const int nt   = (tid >> 6) & 3;
    const int ks   = tid >> 8;                         // 0..127
    const int e    = nt * 16 + (lane & 15);
    const int kb   = ks * 32 + (lane >> 4) * 8;
    float v[8];
    *(float4*)&v[0] = *(const float4*)&gw[(size_t)e * DIM + kb];
    *(float4*)&v[4] = *(const float4*)&gw[(size_t)e * DIM + kb + 4];
    uint4 b0, b1, b2;
    split3_pack(v, b0, b1, b2);
    const size_t base = (size_t)(ks * 4 + nt) * 3 * 64 + lane;
    wS[base] = b0; wS[base + 64] = b1; wS[base + 128] = b2;
}

#define MFMA6(A0, A1, A2, B0, B1, B2, ACC) do {                              \
    ACC = __builtin_amdgcn_mfma_f32_16x16x32_bf16(A2, B0, ACC, 0, 0, 0);     \
    ACC = __builtin_amdgcn_mfma_f32_16x16x32_bf16(A1, B1, ACC, 0, 0, 0);     \
    ACC = __builtin_amdgcn_mfma_f32_16x16x32_bf16(A0, B2, ACC, 0, 0, 0);     \
    ACC = __builtin_amdgcn_mfma_f32_16x16x32_bf16(A1, B0, ACC, 0, 0, 0);     \
    ACC = __builtin_amdgcn_mfma_f32_16x16x32_bf16(A0, B1, ACC, 0, 0, 0);     \
    ACC = __builtin_amdgcn_mfma_f32_16x16x32_bf16(A0, B0, ACC, 0, 0, 0);     \
} while (0)

// ---- fused: 8 independent waves (32 tok x 64 exp x K/8 each), NO barriers,
// NO staging, NO software pipeline. 16 waves/CU hide latency via pure TLP. ----
__global__ __launch_bounds__(512, 4)
void router_fused(const float* __restrict__ x, const uint4* __restrict__ wS,
                  const float* __restrict__ bias, float* __restrict__ out)
{
    __shared__ float part_lds[SPLITK][32][NE];   // 64 KB
    __shared__ int   hist[NE];

    const int t    = threadIdx.x;
    const int lane = t & 63;
    const int wv   = __builtin_amdgcn_readfirstlane(t >> 6);   // wave == kh, 0..7
    const int r15  = lane & 15;
    const int g    = lane >> 4;
    const int tok0 = blockIdx.x * 32;

    if (t < NE) hist[t] = 0;

    // A sources: lane (r15,g) covers row r15 (+16), k-elems [g*8, g*8+8) per slice
    const float* xr0 = x + (size_t)(tok0 + r15) * DIM + g * 8;
    const float* xr1 = x + (size_t)(tok0 + 16 + r15) * DIM + g * 8;
    const uint4* wq  = wS + lane;

    f32x4 acc[4][2];   // [nt][m-half]
#pragma unroll
    for (int nt = 0; nt < 4; ++nt) {
        acc[nt][0] = (f32x4){0.f, 0.f, 0.f, 0.f};
        acc[nt][1] = (f32x4){0.f, 0.f, 0.f, 0.f};
    }

    const int s0 = wv * NSPW;
#pragma unroll 1
    for (int s = s0; s < s0 + NSPW; ++s) {
        float a8[8];
        uint4 u0, u1, u2;
        *(float4*)&a8[0] = *(const float4*)(xr0 + (size_t)s * 32);
        *(float4*)&a8[4] = *(const float4*)(xr0 + (size_t)s * 32 + 4);
        split3_pack(a8, u0, u1, u2);
        const short8v A0h0 = *(short8v*)&u0, A1h0 = *(short8v*)&u1, A2h0 = *(short8v*)&u2;
        *(float4*)&a8[0] = *(const float4*)(xr1 + (size_t)s * 32);
        *(float4*)&a8[4] = *(const float4*)(xr1 + (size_t)s * 32 + 4);
        split3_pack(a8, u0, u1, u2);
        const short8v A0h1 = *(short8v*)&u0, A1h1 = *(short8v*)&u1, A2h1 = *(short8v*)&u2;
        const size_t sb = (size_t)s * 768;
#pragma unroll
        for (int nt = 0; nt < 4; ++nt) {
            const uint4 b0 = wq[sb + nt * 192];
            const uint4 b1 = wq[sb + nt * 192 + 64];
            const uint4 b2 = wq[sb + nt * 192 + 128];
            MFMA6(A0h0, A1h0, A2h0, *(const short8v*)&b0, *(const short8v*)&b1,
                  *(const short8v*)&b2, acc[nt][0]);
            MFMA6(A0h1, A1h1, A2h1, *(const short8v*)&b0, *(const short8v*)&b1,
                  *(const short8v*)&b2, acc[nt][1]);
        }
    }

    // partials -> LDS (C/D layout proven r4-r14: token = G*16+g*4+q, expert = nt*16+r15)
#pragma unroll
    for (int nt = 0; nt < 4; ++nt)
#pragma unroll
        for (int G = 0; G < 2; ++G)
#pragma unroll
            for (int q = 0; q < 4; ++q)
                part_lds[wv][G * 16 + g * 4 + q][nt * 16 + r15] = acc[nt][G][q];

    __syncthreads();

    // ---- epilogue: 4 tokens per wave; lane == expert; ascending-kh reduce
    // (bit-identical chain to rounds 5-14 -> absmax must be 0.001953125) ----
    const float bias_l = bias[lane];
#pragma unroll 1
    for (int i = 0; i < 4; ++i) {
        const int tok = wv * 4 + i;
        float logit = 0.f;
#pragma unroll
        for (int kh = 0; kh < SPLITK; ++kh)
            logit += part_lds[kh][tok][lane];
        const float s = 1.f / (1.f + expf(-logit));
        float myv  = s + bias_l;
        float outv = 0.f;
        int   outi = 0;
        float sum  = 0.f;
#pragma unroll
        for (int k = 0; k < TOPK; ++k) {
            float cv = myv;
            int   ci = lane;
#pragma unroll
            for (int off = 32; off; off >>= 1) {
                float ov = __shfl_xor(cv, off, 64);
                int   oi = __shfl_xor(ci, off, 64);
                if (ov > cv || (ov == cv && oi < ci)) { cv = ov; ci = oi; }
            }
            float ts = __shfl(s, ci, 64);      // unbiased score of winner
            sum += ts;
            if (lane == k)  { outv = ts; outi = ci; }
            if (lane == ci) { myv = -1e30f; }
        }
        const float denom = sum + 1e-20f;
        const size_t gt = (size_t)tok0 + tok;
        if (lane < TOPK) {
            out[gt * TOPK + lane] = (outv / denom) * ROUTE_SCALE;
            out[(size_t)NTOK * TOPK + gt * TOPK + lane] = (float)outi;
            atomicAdd(&hist[outi], 1);
        }
    }

    __syncthreads();
    if (t < NE) {
        int cgt = hist[t];
        if (cgt) atomicAdd(&out[(size_t)NTOK * TOPK * 2 + t], (float)cgt);
    }
}

extern "C" void kernel_launch(void* const* d_in, const int* in_sizes, int n_in,
                              void* d_out, int out_size, void* d_ws, size_t ws_size,
                              hipStream_t stream)
{
    const float* x    = (const float*)d_in[0];
    const float* gw   = (const float*)d_in[1];
    const float* bias = (const float*)d_in[2];
    float* out = (float*)d_out;
    uint4* wS  = (uint4*)d_ws;   // 1.5 MB

    // histogram region must start at zero every call
    hipMemsetAsync(out + (size_t)NTOK * TOPK * 2, 0, NE * sizeof(float), stream);

    prep_w<<<128, 256, 0, stream>>>(gw, wS);
    router_fused<<<NTOK / 32, 512, 0, stream>>>(x, wS, bias, out);
}

// Round 17
// 97.435 us; speedup vs baseline: 2.1066x; 1.0244x over previous
//
#include <hip/hip_runtime.h>
#include <math.h>

#define NTOK 16384
#define DIM  4096
#define NE   64
#define TOPK 8
#define SPLITK 8
#define NSPW 16                  // k32-slices per wave
#define ROUTE_SCALE 2.5f

typedef __attribute__((ext_vector_type(8))) short short8v;
typedef __attribute__((ext_vector_type(4))) float f32x4;

// exact 3-term bf16 truncation split of 8 f32, packed as 3x short8 (bf16) frags
__device__ __forceinline__ void split3_pack(const float* v, uint4& b0, uint4& b1, uint4& b2)
{
    uint p0[8], p1[8], p2[8];
#pragma unroll
    for (int j = 0; j < 8; ++j) {
        const float xv = v[j];
        const uint  u0 = __float_as_uint(xv) & 0xffff0000u;
        const float f0 = __uint_as_float(u0);
        const float r  = xv - f0;                       // exact
        const uint  u1 = __float_as_uint(r) & 0xffff0000u;
        const float f1 = __uint_as_float(u1);
        const float r2 = r - f1;                        // exact, fits bf16
        const uint  u2 = __float_as_uint(r2) & 0xffff0000u;
        p0[j] = u0; p1[j] = u1; p2[j] = u2;
    }
    b0 = make_uint4(p0[1] | (p0[0] >> 16), p0[3] | (p0[2] >> 16),
                    p0[5] | (p0[4] >> 16), p0[7] | (p0[6] >> 16));
    b1 = make_uint4(p1[1] | (p1[0] >> 16), p1[3] | (p1[2] >> 16),
                    p1[5] | (p1[4] >> 16), p1[7] | (p1[6] >> 16));
    b2 = make_uint4(p2[1] | (p2[0] >> 16), p2[3] | (p2[2] >> 16),
                    p2[5] | (p2[4] >> 16), p2[7] | (p2[6] >> 16));
}

// ---- prep: w -> frag-ready bf16 splits (UNCHANGED, proven r4-r16) ----
__global__ __launch_bounds__(256)
void prep_w(const float* __restrict__ gw, uint4* __restrict__ wS)
{
    const int tid  = blockIdx.x * 256 + threadIdx.x;   // 32768 total
    const int lane = tid & 63;
    const int nt   = (tid >> 6) & 3;
    const int ks   = tid >> 8;                         // 0..127
    const int e    = nt * 16 + (lane & 15);
    const int kb   = ks * 32 + (lane >> 4) * 8;
    float v[8];
    *(float4*)&v[0] = *(const float4*)&gw[(size_t)e * DIM + kb];
    *(float4*)&v[4] = *(const float4*)&gw[(size_t)e * DIM + kb + 4];
    uint4 b0, b1, b2;
    split3_pack(v, b0, b1, b2);
    const size_t base = (size_t)(ks * 4 + nt) * 3 * 64 + lane;
    wS[base] = b0; wS[base + 64] = b1; wS[base + 128] = b2;
}

__device__ __forceinline__ void gld_lds16(const float* g, float* l)
{
    __builtin_amdgcn_global_load_lds(
        (const __attribute__((address_space(1))) unsigned int*)g,
        (__attribute__((address_space(3))) unsigned int*)l,
        16, 0, 0);
}

#define MFMA6(A0, A1, A2, B0, B1, B2, ACC) do {                              \
    ACC = __builtin_amdgcn_mfma_f32_16x16x32_bf16(A2, B0, ACC, 0, 0, 0);     \
    ACC = __builtin_amdgcn_mfma_f32_16x16x32_bf16(A1, B1, ACC, 0, 0, 0);     \
    ACC = __builtin_amdgcn_mfma_f32_16x16x32_bf16(A0, B2, ACC, 0, 0, 0);     \
    ACC = __builtin_amdgcn_mfma_f32_16x16x32_bf16(A1, B0, ACC, 0, 0, 0);     \
    ACC = __builtin_amdgcn_mfma_f32_16x16x32_bf16(A0, B1, ACC, 0, 0, 0);     \
    ACC = __builtin_amdgcn_mfma_f32_16x16x32_bf16(A0, B0, ACC, 0, 0, 0);     \
} while (0)

#define SB __builtin_amdgcn_sched_barrier(0)
#define WAITV(N) do { SB; asm volatile("s_waitcnt vmcnt(" #N ")" ::: "memory"); SB; } while (0)

// ---- fused: r16 geometry (8 kh-waves x 32 tok, no cross-wave sync in hot loop)
// + wave-PRIVATE 2-slot LDS DMA ring with counted vmcnt (allocator-proof depth).
__global__ __launch_bounds__(512, 4)
void router_fused(const float* __restrict__ x, const uint4* __restrict__ wS,
                  const float* __restrict__ bias, float* __restrict__ out)
{
    __shared__ float pool[SPLITK * 2 * 1024];   // 64 KB: DMA ring; partials after loop
    __shared__ int   hist[NE];

    const int t    = threadIdx.x;
    const int lane = t & 63;
    const int wv   = __builtin_amdgcn_readfirstlane(t >> 6);   // wave == kh, 0..7
    const int r15  = lane & 15;
    const int g    = lane >> 4;
    const int tok0 = blockIdx.x * 32;
    const int ks0  = wv * NSPW;

    if (t < NE) hist[t] = 0;

    // DMA source per lane: inst j covers rows 8j..8j+7; lane l -> row 8j+(l>>3),
    // swizzled 16B piece (l&7)^(l>>3) (m173: pre-swizzled source, linear LDS dest)
    const int lr  = lane >> 3;
    const int swz = (lane & 7) ^ lr;
    const float* gsrc0 = x + (size_t)(tok0 +  0 + lr) * DIM + ks0 * 32 + swz * 4;
    const float* gsrc1 = x + (size_t)(tok0 +  8 + lr) * DIM + ks0 * 32 + swz * 4;
    const float* gsrc2 = x + (size_t)(tok0 + 16 + lr) * DIM + ks0 * 32 + swz * 4;
    const float* gsrc3 = x + (size_t)(tok0 + 24 + lr) * DIM + ks0 * 32 + swz * 4;

    const uint4* wq = wS + lane;

    f32x4 acc[4][2];
#pragma unroll
    for (int nt = 0; nt < 4; ++nt) {
        acc[nt][0] = (f32x4){0.f, 0.f, 0.f, 0.f};
        acc[nt][1] = (f32x4){0.f, 0.f, 0.f, 0.f};
    }
    uint4 B[12];

    // reader constants: row r=h*16+r15 -> group j=h*2+(r15>>3), R=r15&7, pieces (2g)^R,(2g+1)^R
    const int jr = r15 >> 3;
    const int R  = r15 & 7;
    const int q0 = (2 * g) ^ R;
    const int q1 = (2 * g + 1) ^ R;

#define DMAC(c) do {                                                         \
        float* ldst = &pool[(size_t)(wv * 2 + ((c) & 1)) * 1024];            \
        gld_lds16(gsrc0 + (size_t)(c) * 32, ldst);                           \
        gld_lds16(gsrc1 + (size_t)(c) * 32, ldst + 256);                     \
        gld_lds16(gsrc2 + (size_t)(c) * 32, ldst + 512);                     \
        gld_lds16(gsrc3 + (size_t)(c) * 32, ldst + 768);                     \
    } while (0)
#define LOADB(cg) do {                                                       \
        const size_t sgb = (size_t)(ks0 + (cg)) * 768;                       \
        _Pragma("unroll")                                                    \
        for (int nt = 0; nt < 4; ++nt)                                       \
            _Pragma("unroll")                                                \
            for (int sp = 0; sp < 3; ++sp)                                   \
                B[nt * 3 + sp] = wq[sgb + nt * 192 + sp * 64];               \
    } while (0)

    // prologue: B(0) first (monotone need-order), then DMA(0), DMA(1)
    LOADB(0);
    DMAC(0);
    DMAC(1);

#pragma unroll 1
    for (int c = 0; c < NSPW; ++c) {
        if (c == NSPW - 1) { WAITV(0); } else { WAITV(4); }   // DMA(c)+B(c) done; DMA(c+1) in flight
        // ---- compute slice c from ring slot c&1 ----
        {
            const float* sbase = &pool[(size_t)(wv * 2 + (c & 1)) * 1024];
            float a8[8]; uint4 u0, u1, u2;
            *(float4*)&a8[0] = *(const float4*)&sbase[jr * 256 + R * 32 + q0 * 4];
            *(float4*)&a8[4] = *(const float4*)&sbase[jr * 256 + R * 32 + q1 * 4];
            split3_pack(a8, u0, u1, u2);
            const short8v A0h0 = *(short8v*)&u0, A1h0 = *(short8v*)&u1, A2h0 = *(short8v*)&u2;
            *(float4*)&a8[0] = *(const float4*)&sbase[(jr + 2) * 256 + R * 32 + q0 * 4];
            *(float4*)&a8[4] = *(const float4*)&sbase[(jr + 2) * 256 + R * 32 + q1 * 4];
            split3_pack(a8, u0, u1, u2);
            const short8v A0h1 = *(short8v*)&u0, A1h1 = *(short8v*)&u1, A2h1 = *(short8v*)&u2;
#pragma unroll
            for (int nt = 0; nt < 4; ++nt) {
                MFMA6(A0h0, A1h0, A2h0, *(const short8v*)&B[nt * 3 + 0],
                      *(const short8v*)&B[nt * 3 + 1], *(const short8v*)&B[nt * 3 + 2],
                      acc[nt][0]);
                MFMA6(A0h1, A1h1, A2h1, *(const short8v*)&B[nt * 3 + 0],
                      *(const short8v*)&B[nt * 3 + 1], *(const short8v*)&B[nt * 3 + 2],
                      acc[nt][1]);
            }
        }
        SB;
        if (c + 1 < NSPW) LOADB(c + 1);      // needed next turn: issued BEFORE later DMA
        SB;
        if (c + 2 < NSPW) DMAC(c + 2);       // into slot (c&1), just freed by this compute
        SB;
    }
#undef DMAC
#undef LOADB

    // ---- partials -> pool (aliased; all DMA drained by WAITV(0) above) ----
    float (*part)[32][NE] = (float (*)[32][NE])pool;
#pragma unroll
    for (int nt = 0; nt < 4; ++nt)
#pragma unroll
        for (int G = 0; G < 2; ++G)
#pragma unroll
            for (int q = 0; q < 4; ++q)
                part[wv][G * 16 + g * 4 + q][nt * 16 + r15] = acc[nt][G][q];

    __syncthreads();

    // ---- epilogue (identical chain to r16: ascending-kh reduce -> bit-identical) ----
    const float bias_l = bias[lane];
#pragma unroll 1
    for (int i = 0; i < 4; ++i) {
        const int tok = wv * 4 + i;
        float logit = 0.f;
#pragma unroll
        for (int kh = 0; kh < SPLITK; ++kh)
            logit += part[kh][tok][lane];
        const float s = 1.f / (1.f + expf(-logit));
        float myv  = s + bias_l;
        float outv = 0.f;
        int   outi = 0;
        float sum  = 0.f;
#pragma unroll
        for (int k = 0; k < TOPK; ++k) {
            float cv = myv;
            int   ci = lane;
#pragma unroll
            for (int off = 32; off; off >>= 1) {
                float ov = __shfl_xor(cv, off, 64);
                int   oi = __shfl_xor(ci, off, 64);
                if (ov > cv || (ov == cv && oi < ci)) { cv = ov; ci = oi; }
            }
            float ts = __shfl(s, ci, 64);      // unbiased score of winner
            sum += ts;
            if (lane == k)  { outv = ts; outi = ci; }
            if (lane == ci) { myv = -1e30f; }
        }
        const float denom = sum + 1e-20f;
        const size_t gt = (size_t)tok0 + tok;
        if (lane < TOPK) {
            out[gt * TOPK + lane] = (outv / denom) * ROUTE_SCALE;
            out[(size_t)NTOK * TOPK + gt * TOPK + lane] = (float)outi;
            atomicAdd(&hist[outi], 1);
        }
    }

    __syncthreads();
    if (t < NE) {
        int cgt = hist[t];
        if (cgt) atomicAdd(&out[(size_t)NTOK * TOPK * 2 + t], (float)cgt);
    }
}

extern "C" void kernel_launch(void* const* d_in, const int* in_sizes, int n_in,
                              void* d_out, int out_size, void* d_ws, size_t ws_size,
                              hipStream_t stream)
{
    const float* x    = (const float*)d_in[0];
    const float* gw   = (const float*)d_in[1];
    const float* bias = (const float*)d_in[2];
    float* out = (float*)d_out;
    uint4* wS  = (uint4*)d_ws;   // 1.5 MB

    // histogram region must start at zero every call
    hipMemsetAsync(out + (size_t)NTOK * TOPK * 2, 0, NE * sizeof(float), stream);

    prep_w<<<128, 256, 0, stream>>>(gw, wS);
    router_fused<<<NTOK / 32, 512, 0, stream>>>(x, wS, bias, out);
}

// Round 18
// 94.729 us; speedup vs baseline: 2.1668x; 1.0286x over previous
//
#include <hip/hip_runtime.h>
#include <math.h>

#define NTOK 16384
#define DIM  4096
#define NE   64
#define TOPK 8
#define SPLITK 8
#define NSPW 16                  // k32-slices per wave
#define ROUTE_SCALE 2.5f

typedef __attribute__((ext_vector_type(8))) short short8v;
typedef __attribute__((ext_vector_type(4))) float f32x4;

// exact 3-term bf16 truncation split of 8 f32, packed as 3x short8 (bf16) frags
__device__ __forceinline__ void split3_pack(const float* v, uint4& b0, uint4& b1, uint4& b2)
{
    uint p0[8], p1[8], p2[8];
#pragma unroll
    for (int j = 0; j < 8; ++j) {
        const float xv = v[j];
        const uint  u0 = __float_as_uint(xv) & 0xffff0000u;
        const float f0 = __uint_as_float(u0);
        const float r  = xv - f0;                       // exact
        const uint  u1 = __float_as_uint(r) & 0xffff0000u;
        const float f1 = __uint_as_float(u1);
        const float r2 = r - f1;                        // exact, fits bf16
        const uint  u2 = __float_as_uint(r2) & 0xffff0000u;
        p0[j] = u0; p1[j] = u1; p2[j] = u2;
    }
    b0 = make_uint4(p0[1] | (p0[0] >> 16), p0[3] | (p0[2] >> 16),
                    p0[5] | (p0[4] >> 16), p0[7] | (p0[6] >> 16));
    b1 = make_uint4(p1[1] | (p1[0] >> 16), p1[3] | (p1[2] >> 16),
                    p1[5] | (p1[4] >> 16), p1[7] | (p1[6] >> 16));
    b2 = make_uint4(p2[1] | (p2[0] >> 16), p2[3] | (p2[2] >> 16),
                    p2[5] | (p2[4] >> 16), p2[7] | (p2[6] >> 16));
}

// ---- prep: w -> frag-ready bf16 splits (UNCHANGED, proven r4-r17) ----
__global__ __launch_bounds__(256)
void prep_w(const float* __restrict__ gw, uint4* __restrict__ wS)
{
    const int tid  = blockIdx.x * 256 + threadIdx.x;   // 32768 total
    const int lane = tid & 63;
    const int nt   = (tid >> 6) & 3;
    const int ks   = tid >> 8;                         // 0..127
    const int e    = nt * 16 + (lane & 15);
    const int kb   = ks * 32 + (lane >> 4) * 8;
    float v[8];
    *(float4*)&v[0] = *(const float4*)&gw[(size_t)e * DIM + kb];
    *(float4*)&v[4] = *(const float4*)&gw[(size_t)e * DIM + kb + 4];
    uint4 b0, b1, b2;
    split3_pack(v, b0, b1, b2);
    const size_t base = (size_t)(ks * 4 + nt) * 3 * 64 + lane;
    wS[base] = b0; wS[base + 64] = b1; wS[base + 128] = b2;
}

__device__ __forceinline__ void gld_lds16(const float* g, float* l)
{
    __builtin_amdgcn_global_load_lds(
        (const __attribute__((address_space(1))) unsigned int*)g,
        (__attribute__((address_space(3))) unsigned int*)l,
        16, 0, 0);
}

#define MFMA6(A0, A1, A2, B0, B1, B2, ACC) do {                              \
    ACC = __builtin_amdgcn_mfma_f32_16x16x32_bf16(A2, B0, ACC, 0, 0, 0);     \
    ACC = __builtin_amdgcn_mfma_f32_16x16x32_bf16(A1, B1, ACC, 0, 0, 0);     \
    ACC = __builtin_amdgcn_mfma_f32_16x16x32_bf16(A0, B2, ACC, 0, 0, 0);     \
    ACC = __builtin_amdgcn_mfma_f32_16x16x32_bf16(A1, B0, ACC, 0, 0, 0);     \
    ACC = __builtin_amdgcn_mfma_f32_16x16x32_bf16(A0, B1, ACC, 0, 0, 0);     \
    ACC = __builtin_amdgcn_mfma_f32_16x16x32_bf16(A0, B0, ACC, 0, 0, 0);     \
} while (0)

#define SB __builtin_amdgcn_sched_barrier(0)
#define WAITV(N) do { SB; asm volatile("s_waitcnt vmcnt(" #N ")" ::: "memory"); SB; } while (0)

// ---- fused: r17 geometry + sub-turn B rotation (constant vmcnt(13) phases,
// full-turn B lead, zero extra VGPRs) + setprio around MFMA clusters ----
__global__ __launch_bounds__(512, 4)
void router_fused(const float* __restrict__ x, const uint4* __restrict__ wS,
                  const float* __restrict__ bias, float* __restrict__ out)
{
    __shared__ float pool[SPLITK * 2 * 1024];   // 64 KB: DMA ring; partials after loop
    __shared__ int   hist[NE];

    const int t    = threadIdx.x;
    const int lane = t & 63;
    const int wv   = __builtin_amdgcn_readfirstlane(t >> 6);   // wave == kh, 0..7
    const int r15  = lane & 15;
    const int g    = lane >> 4;
    const int tok0 = blockIdx.x * 32;
    const int ks0  = wv * NSPW;

    if (t < NE) hist[t] = 0;

    // DMA source per lane (m173 pre-swizzle, linear LDS dest) — proven r17
    const int lr  = lane >> 3;
    const int swz = (lane & 7) ^ lr;
    const float* gsrc0 = x + (size_t)(tok0 +  0 + lr) * DIM + ks0 * 32 + swz * 4;
    const float* gsrc1 = x + (size_t)(tok0 +  8 + lr) * DIM + ks0 * 32 + swz * 4;
    const float* gsrc2 = x + (size_t)(tok0 + 16 + lr) * DIM + ks0 * 32 + swz * 4;
    const float* gsrc3 = x + (size_t)(tok0 + 24 + lr) * DIM + ks0 * 32 + swz * 4;

    const uint4* wq = wS + lane;

    f32x4 acc[4][2];
#pragma unroll
    for (int nt = 0; nt < 4; ++nt) {
        acc[nt][0] = (f32x4){0.f, 0.f, 0.f, 0.f};
        acc[nt][1] = (f32x4){0.f, 0.f, 0.f, 0.f};
    }
    uint4 B[12];

    const int jr = r15 >> 3;
    const int R  = r15 & 7;
    const int q0 = (2 * g) ^ R;
    const int q1 = (2 * g + 1) ^ R;

#define DMAC(c) do {                                                         \
        float* ldst = &pool[(size_t)(wv * 2 + ((c) & 1)) * 1024];            \
        gld_lds16(gsrc0 + (size_t)(c) * 32, ldst);                           \
        gld_lds16(gsrc1 + (size_t)(c) * 32, ldst + 256);                     \
        gld_lds16(gsrc2 + (size_t)(c) * 32, ldst + 512);                     \
        gld_lds16(gsrc3 + (size_t)(c) * 32, ldst + 768);                     \
    } while (0)
#define LOADBNT(nt, cg) do {                                                 \
        const size_t sgb = (size_t)(ks0 + (cg)) * 768 + (nt) * 192;          \
        B[(nt) * 3 + 0] = wq[sgb];                                           \
        B[(nt) * 3 + 1] = wq[sgb + 64];                                      \
        B[(nt) * 3 + 2] = wq[sgb + 128];                                     \
    } while (0)
// A-prep: declares A frags for slice c in current scope
#define APREP(c)                                                             \
        const float* sbase = &pool[(size_t)(wv * 2 + ((c) & 1)) * 1024];     \
        float a8[8]; uint4 u0, u1, u2;                                       \
        *(float4*)&a8[0] = *(const float4*)&sbase[jr * 256 + R * 32 + q0 * 4];       \
        *(float4*)&a8[4] = *(const float4*)&sbase[jr * 256 + R * 32 + q1 * 4];       \
        split3_pack(a8, u0, u1, u2);                                         \
        const short8v A0h0 = *(short8v*)&u0, A1h0 = *(short8v*)&u1, A2h0 = *(short8v*)&u2; \
        *(float4*)&a8[0] = *(const float4*)&sbase[(jr + 2) * 256 + R * 32 + q0 * 4]; \
        *(float4*)&a8[4] = *(const float4*)&sbase[(jr + 2) * 256 + R * 32 + q1 * 4]; \
        split3_pack(a8, u0, u1, u2);                                         \
        const short8v A0h1 = *(short8v*)&u0, A1h1 = *(short8v*)&u1, A2h1 = *(short8v*)&u2;
#define PHASE(nt) do {                                                       \
        __builtin_amdgcn_s_setprio(1);                                       \
        MFMA6(A0h0, A1h0, A2h0, *(const short8v*)&B[(nt)*3+0],               \
              *(const short8v*)&B[(nt)*3+1], *(const short8v*)&B[(nt)*3+2],  \
              acc[nt][0]);                                                   \
        MFMA6(A0h1, A1h1, A2h1, *(const short8v*)&B[(nt)*3+0],               \
              *(const short8v*)&B[(nt)*3+1], *(const short8v*)&B[(nt)*3+2],  \
              acc[nt][1]);                                                   \
        __builtin_amdgcn_s_setprio(0);                                       \
    } while (0)

    // ---- prologue: D(0), B(0) by nt, D(1) — FIFO matches steady count 13 ----
    DMAC(0);
    LOADBNT(0, 0); LOADBNT(1, 0); LOADBNT(2, 0); LOADBNT(3, 0);
    DMAC(1);

    // ---- steady turns c = 0..14 (B(c+1) rotated in per phase; DMA(c+2)) ----
#pragma unroll 1
    for (int c = 0; c < NSPW - 1; ++c) {
        WAITV(13);               // retires through B_nt0(c) (incl. DMA(c))
        APREP(c);
        PHASE(0); LOADBNT(0, c + 1); WAITV(13);
        PHASE(1); LOADBNT(1, c + 1); WAITV(13);
        PHASE(2); LOADBNT(2, c + 1); WAITV(13);
        PHASE(3); LOADBNT(3, c + 1);
        if (c + 2 < NSPW) DMAC(c + 2);
    }
    // ---- tail turn c = 15: no loads left; drain 9/6/3/0 ----
    {
        WAITV(9);
        APREP(NSPW - 1);
        PHASE(0); WAITV(6);
        PHASE(1); WAITV(3);
        PHASE(2); WAITV(0);
        PHASE(3);
    }
#undef DMAC
#undef LOADBNT
#undef APREP
#undef PHASE

    // ---- partials -> pool (all DMA drained by WAITV(0)) ----
    float (*part)[32][NE] = (float (*)[32][NE])pool;
#pragma unroll
    for (int nt = 0; nt < 4; ++nt)
#pragma unroll
        for (int G = 0; G < 2; ++G)
#pragma unroll
            for (int q = 0; q < 4; ++q)
                part[wv][G * 16 + g * 4 + q][nt * 16 + r15] = acc[nt][G][q];

    __syncthreads();

    // ---- epilogue (identical chain r16/r17: ascending-kh reduce -> bit-identical) ----
    const float bias_l = bias[lane];
#pragma unroll 1
    for (int i = 0; i < 4; ++i) {
        const int tok = wv * 4 + i;
        float logit = 0.f;
#pragma unroll
        for (int kh = 0; kh < SPLITK; ++kh)
            logit += part[kh][tok][lane];
        const float s = 1.f / (1.f + expf(-logit));
        float myv  = s + bias_l;
        float outv = 0.f;
        int   outi = 0;
        float sum  = 0.f;
#pragma unroll
        for (int k = 0; k < TOPK; ++k) {
            float cv = myv;
            int   ci = lane;
#pragma unroll
            for (int off = 32; off; off >>= 1) {
                float ov = __shfl_xor(cv, off, 64);
                int   oi = __shfl_xor(ci, off, 64);
                if (ov > cv || (ov == cv && oi < ci)) { cv = ov; ci = oi; }
            }
            float ts = __shfl(s, ci, 64);      // unbiased score of winner
            sum += ts;
            if (lane == k)  { outv = ts; outi = ci; }
            if (lane == ci) { myv = -1e30f; }
        }
        const float denom = sum + 1e-20f;
        const size_t gt = (size_t)tok0 + tok;
        if (lane < TOPK) {
            out[gt * TOPK + lane] = (outv / denom) * ROUTE_SCALE;
            out[(size_t)NTOK * TOPK + gt * TOPK + lane] = (float)outi;
            atomicAdd(&hist[outi], 1);
        }
    }

    __syncthreads();
    if (t < NE) {
        int cgt = hist[t];
        if (cgt) atomicAdd(&out[(size_t)NTOK * TOPK * 2 + t], (float)cgt);
    }
}

extern "C" void kernel_launch(void* const* d_in, const int* in_sizes, int n_in,
                              void* d_out, int out_size, void* d_ws, size_t ws_size,
                              hipStream_t stream)
{
    const float* x    = (const float*)d_in[0];
    const float* gw   = (const float*)d_in[1];
    const float* bias = (const float*)d_in[2];
    float* out = (float*)d_out;
    uint4* wS  = (uint4*)d_ws;   // 1.5 MB

    // histogram region must start at zero every call
    hipMemsetAsync(out + (size_t)NTOK * TOPK * 2, 0, NE * sizeof(float), stream);

    prep_w<<<128, 256, 0, stream>>>(gw, wS);
    router_fused<<<NTOK / 32, 512, 0, stream>>>(x, wS, bias, out);
}